// Round 3
// baseline (1988.466 us; speedup 1.0000x reference)
//
#include <hip/hip_runtime.h>

typedef __bf16 bf16x8 __attribute__((ext_vector_type(8)));
typedef __bf16 bf16x4 __attribute__((ext_vector_type(4)));
typedef __bf16 bf16x2 __attribute__((ext_vector_type(2)));
typedef float  f32x4  __attribute__((ext_vector_type(4)));

#define NG 5000
#define NU 100000
#define NI 20000
#define H  128
#define EUG 300000
#define EUI 600000
#define EGI 200000
#define ETOT (EUG + EGI + EUI + EUI)   // 1,700,000
#define NN  (2 * NG + NU + NI)         // 130,000 concatenated nodes

// ---------------- workspace layout (bytes) ----------------
#define B_EMBU  0UL            // NU*H bf16
#define B_EMBI  25600000UL     // NI*H bf16
#define B_AGGU  30720000UL     // NU*H bf16  (i->u mean of embI, then hu1 in-place)
#define B_AGGI  56320000UL     // NI*H bf16  (u->i mean, then hi1 in-place)
#define B_AGGG1 61440000UL     // NG*H bf16  (u->g mean L1)
#define B_AGGG2 62720000UL     // NG*H bf16  (i->g mean L1)
#define B_HG1   64000000UL     // NG*H bf16
#define B_GU    65280000UL     // NG*H bf16 (L2 u->g of hu1)
#define B_GI    66560000UL     // NG*H bf16 (L2 i->g of hi1)
#define B_REP   67840000UL     // NG*H bf16 (relu(og2))
#define B_BC    69120000UL     // 4*128 f32
#define B_PWT   69122048UL     // NI*H bf16
#define B_WT    74242048UL     // 9*16384 bf16 -> ends 74,536,960
#define B_BAR   74536960UL     // 128 B: [0]=counter, [+64]=generation
#define B_CNT   74537088UL     // NN int
#define B_OFFS  75057088UL     // NN+1 int (+pad)
#define B_CUR   75577104UL     // NN int
#define B_EIDX  76097104UL     // ETOT int -> end 82,897,104

// chunksum (64 ints) overlaps B_AGGU: dead until seg1 phase; ordered by barriers.

#define SCAN_CHUNK 2048
#define NCHUNK 64

// phase1 virtual-block ranges
#define NB_PREP 10
#define NB_TP   626      // 313 x 2
#define NB_CVU  12500    // NU*32/256
#define NB_CVI  2500     // NI*32/256
#define NB_HIST 6641     // ceil(ETOT/256)
#define NB_P1   (NB_PREP + NB_TP + NB_CVU + NB_CVI + NB_HIST)

// gemm virtual-block counts
#define NBU 782
#define NBI 157
#define NBG 40

#define GRID_B 768    // 3 blocks/CU asked; capacity 4 (VGPR<=128 via bounds, LDS 16.7KB)
#define GRID_C 384    // 1.5 blocks/CU asked; capacity 2 (LDS 64KB, VGPR<=256)

// ---------------- global barrier (agent-scope atomics; graph-capture safe) ----
// Relative generations: works from any starting gen as long as counter==0 on entry.
__device__ __forceinline__ void gbar(int* bar, int nb) {
  __syncthreads();
  if (threadIdx.x == 0) {
    int* cnt = bar;
    int* gen = bar + 16;   // separate cacheline
    int g = __hip_atomic_load(gen, __ATOMIC_RELAXED, __HIP_MEMORY_SCOPE_AGENT);
    if (__hip_atomic_fetch_add(cnt, 1, __ATOMIC_ACQ_REL, __HIP_MEMORY_SCOPE_AGENT) == nb - 1) {
      __hip_atomic_store(cnt, 0, __ATOMIC_RELAXED, __HIP_MEMORY_SCOPE_AGENT);
      __hip_atomic_store(gen, g + 1, __ATOMIC_RELEASE, __HIP_MEMORY_SCOPE_AGENT);
    } else {
      int spins = 0;
      while (__hip_atomic_load(gen, __ATOMIC_ACQUIRE, __HIP_MEMORY_SCOPE_AGENT) == g) {
        __builtin_amdgcn_s_sleep(8);
        if (++spins > (1 << 16)) break;   // ~14ms failsafe: fail loud, never hang
      }
    }
  }
  __syncthreads();
}

// XOR-swizzled LDS index (8-elem bf16 chunks)
__device__ __forceinline__ int swz(int row, int k) {
  return ((((k >> 3) ^ (row & 15)) << 3) | (k & 7));
}
// fp32 epilogue swizzle
__device__ __forceinline__ int cswz(int row, int col) {
  return col ^ (((row >> 2) & 1) << 4);
}

// ---------------- device bodies ----------------
__device__ void prep_dev(const float* __restrict__ W1l, const float* __restrict__ W1r,
                         const float* __restrict__ W2l, const float* __restrict__ W2r,
                         const float* __restrict__ b1, const float* __restrict__ b2,
                         __bf16* __restrict__ WT, float* __restrict__ bc, int b, int tid) {
  if (b < 9) {
    const float* Wa; const float* Wb = nullptr;
    switch (b) {
      case 0: Wa = W1r + 1 * 16384; Wb = W1r + 3 * 16384; break;  // hu1: emb term
      case 1: Wa = W1l + 3 * 16384; break;                        // hu1: agg term
      case 2: Wa = W1l + 2 * 16384; break;                        // hi1: agg term
      case 3: Wa = W1r + 2 * 16384; Wb = W1r + 4 * 16384; break;  // hi1: emb term
      case 4: Wa = W1l + 0 * 16384; break;                        // hg1: u->g
      case 5: Wa = W1l + 5 * 16384; break;                        // hg1: i->g
      case 6: Wa = W2r + 0 * 16384; Wb = W2r + 5 * 16384; break;  // og2: hg1 term
      case 7: Wa = W2l + 0 * 16384; break;                        // og2: gU term
      default: Wa = W2l + 5 * 16384; break;                       // og2: gI term
    }
    __bf16* dst = WT + b * 16384;
    for (int idx = tid; idx < 16384; idx += 256) {
      int k = idx >> 7, c = idx & 127;
      float v = Wa[idx];
      if (Wb) v += Wb[idx];
      dst[c * 128 + k] = (__bf16)v;
    }
  } else {
    if (tid < 128) {
      bc[tid]       = b1[128 + tid]     + b1[3 * 128 + tid];  // user
      bc[128 + tid] = b1[2 * 128 + tid] + b1[4 * 128 + tid];  // item
      bc[256 + tid] = b1[tid]           + b1[5 * 128 + tid];  // group L1
      bc[384 + tid] = b2[tid]           + b2[5 * 128 + tid];  // group L2
    }
  }
}

__device__ void transpose_dev(const float* __restrict__ pw, __bf16* __restrict__ pwt,
                              int bx, int by, int tid, float (*t)[65]) {
  int i0 = bx * 64, k0 = by * 64;
  for (int idx = tid; idx < 64 * 16; idx += 256) {
    int kk = idx >> 4, c4 = (idx & 15) << 2;
    int ib = i0 + c4;
    float x0 = 0.f, x1 = 0.f, x2 = 0.f, x3 = 0.f;
    const float* src = pw + (size_t)(k0 + kk) * NI + ib;
    if (ib + 3 < NI) {
      const float4 v = *(const float4*)src;
      x0 = v.x; x1 = v.y; x2 = v.z; x3 = v.w;
    } else {
      if (ib + 0 < NI) x0 = src[0];
      if (ib + 1 < NI) x1 = src[1];
      if (ib + 2 < NI) x2 = src[2];
      if (ib + 3 < NI) x3 = src[3];
    }
    t[kk][c4 + 0] = x0; t[kk][c4 + 1] = x1; t[kk][c4 + 2] = x2; t[kk][c4 + 3] = x3;
  }
  __syncthreads();
  for (int idx = tid; idx < 64 * 16; idx += 256) {
    int ii = idx >> 4, k4 = (idx & 15) << 2;
    int gi = i0 + ii;
    if (gi < NI) {
      bf16x4 o;
      o[0] = (__bf16)t[k4 + 0][ii]; o[1] = (__bf16)t[k4 + 1][ii];
      o[2] = (__bf16)t[k4 + 2][ii]; o[3] = (__bf16)t[k4 + 3][ii];
      *(bf16x4*)(pwt + (size_t)gi * 128 + k0 + k4) = o;
    }
  }
  __syncthreads();   // protect t[] reuse across virtual-block iterations
}

__device__ void cvt_dev(const float* __restrict__ src, __bf16* __restrict__ dst,
                        int b, int tid, int n4) {
  int i = b * 256 + tid;
  if (i < n4) {
    float4 v = ((const float4*)src)[i];
    bf16x4 o;
    o[0] = (__bf16)v.x; o[1] = (__bf16)v.y; o[2] = (__bf16)v.z; o[3] = (__bf16)v.w;
    ((bf16x4*)dst)[i] = o;
  }
}

__device__ void hist_dev(const int* __restrict__ ug_dst, const int* __restrict__ gi_src,
                         const int* __restrict__ ui_src, const int* __restrict__ ui_dst,
                         int* __restrict__ cnt, int b, int tid) {
  int i = b * 256 + tid;
  int key, base;
  if (i < EUG)                       { key = ug_dst[i];                   base = 0; }
  else if (i < EUG + EGI)            { key = gi_src[i - EUG];             base = NG; }
  else if (i < EUG + EGI + EUI)      { key = ui_src[i - EUG - EGI];       base = 2 * NG; }
  else if (i < ETOT)                 { key = ui_dst[i - EUG - EGI - EUI]; base = 2 * NG + NU; }
  else return;
  atomicAdd(&cnt[base + key], 1);
}

// ---------------- fused GEMM core ----------------
// C = act(sum_t A_t @ B_t + bias). A:[N,128] bf16 rm, B:[NC,128] bf16 [col][k].
__device__ void gemm_core(const __bf16* __restrict__ A0, const __bf16* __restrict__ B0,
                          const __bf16* __restrict__ A1, const __bf16* __restrict__ B1,
                          const __bf16* __restrict__ A2, const __bf16* __restrict__ B2,
                          const float* __restrict__ bias,
                          float* __restrict__ Cf, __bf16* __restrict__ Cb,
                          int N, int NC, int nterms, int relu,
                          int rowblk, int colblk, char* smem_raw) {
  __bf16* sA = (__bf16*)smem_raw;
  __bf16* sB = sA + 128 * 128;
  float* sC = (float*)smem_raw;
  int tid = threadIdx.x;
  int rowbase = rowblk * 128, colbase = colblk * 128;
  int wid = tid >> 6, lane = tid & 63;
  int qrow = (wid >> 1) << 6, qcol = (wid & 1) << 6;
  int lrow = lane & 15, quad = lane >> 4;

  f32x4 acc[4][4];
#pragma unroll
  for (int mi = 0; mi < 4; ++mi)
#pragma unroll
    for (int ni = 0; ni < 4; ++ni) acc[mi][ni] = (f32x4){0.f, 0.f, 0.f, 0.f};

  const __bf16* As[3] = {A0, A1, A2};
  const __bf16* Bs[3] = {B0, B1, B2};

  for (int t = 0; t < nterms; ++t) {
    __syncthreads();
    const __bf16* A = As[t];
    for (int idx = tid; idx < 2048; idx += 256) {
      int row = idx >> 4, c8 = (idx & 15) << 3;
      int grow = rowbase + row;
      bf16x8 v;
      if (grow < N) v = *(const bf16x8*)(A + (size_t)grow * 128 + c8);
      else { for (int u = 0; u < 8; ++u) v[u] = (__bf16)0.f; }
      *(bf16x8*)&sA[row * 128 + swz(row, c8)] = v;
    }
    const __bf16* B = Bs[t];
    for (int idx = tid; idx < 2048; idx += 256) {
      int n = idx >> 4, c8 = (idx & 15) << 3;
      int gcol = colbase + n;
      bf16x8 v;
      if (gcol < NC) v = *(const bf16x8*)(B + (size_t)gcol * 128 + c8);
      else { for (int u = 0; u < 8; ++u) v[u] = (__bf16)0.f; }
      *(bf16x8*)&sB[n * 128 + swz(n, c8)] = v;
    }
    __syncthreads();
#pragma unroll
    for (int kb = 0; kb < 4; ++kb) {
      int k0 = kb * 32 + quad * 8;
      bf16x8 af[4], bfr[4];
#pragma unroll
      for (int mi = 0; mi < 4; ++mi) {
        int r = qrow + mi * 16 + lrow;
        af[mi] = *(const bf16x8*)&sA[r * 128 + swz(r, k0)];
      }
#pragma unroll
      for (int ni = 0; ni < 4; ++ni) {
        int r = qcol + ni * 16 + lrow;
        bfr[ni] = *(const bf16x8*)&sB[r * 128 + swz(r, k0)];
      }
#pragma unroll
      for (int mi = 0; mi < 4; ++mi)
#pragma unroll
        for (int ni = 0; ni < 4; ++ni)
          acc[mi][ni] = __builtin_amdgcn_mfma_f32_16x16x32_bf16(af[mi], bfr[ni], acc[mi][ni], 0, 0, 0);
    }
  }

  __syncthreads();
#pragma unroll
  for (int mi = 0; mi < 4; ++mi) {
#pragma unroll
    for (int ni = 0; ni < 4; ++ni) {
      int col = qcol + ni * 16 + lrow;
#pragma unroll
      for (int r = 0; r < 4; ++r) {
        int row = qrow + mi * 16 + quad * 4 + r;
        sC[row * 128 + cswz(row, col)] = acc[mi][ni][r];
      }
    }
  }
  __syncthreads();
  for (int idx = tid; idx < 4096; idx += 256) {
    int row = idx >> 5, c4 = (idx & 31) << 2;
    int grow = rowbase + row, gcol = colbase + c4;
    if (grow >= N) continue;
    f32x4 v = *(const f32x4*)&sC[row * 128 + cswz(row, c4)];
    if (gcol + 3 < NC) {
      if (bias) {
        f32x4 bv = *(const f32x4*)&bias[gcol];
        v += bv;
      }
      if (relu) {
#pragma unroll
        for (int u = 0; u < 4; ++u) v[u] = fmaxf(v[u], 0.f);
      }
      if (Cb) {
        bf16x4 o;
        o[0] = (__bf16)v[0]; o[1] = (__bf16)v[1]; o[2] = (__bf16)v[2]; o[3] = (__bf16)v[3];
        *(bf16x4*)(Cb + (size_t)grow * NC + gcol) = o;
      } else {
        __builtin_nontemporal_store(v, (f32x4*)(Cf + (size_t)grow * NC + gcol));
      }
    } else {
#pragma unroll
      for (int u = 0; u < 4; ++u) {
        if (gcol + u < NC) {
          float x = v[u] + (bias ? bias[gcol + u] : 0.f);
          if (relu) x = fmaxf(x, 0.f);
          if (Cb) Cb[(size_t)grow * NC + gcol + u] = (__bf16)x;
          else    Cf[(size_t)grow * NC + gcol + u] = x;
        }
      }
    }
  }
  __syncthreads();   // protect LDS reuse across virtual-block iterations
}

// ---------------- segment-mean: 2 rows/load (lane-halves x bf16x4) --------
__device__ void seg_dev(const __bf16* __restrict__ feat, const int* __restrict__ offs,
                        const int* __restrict__ eidx, __bf16* __restrict__ out,
                        int node, int orow, int lane) {
  int s = offs[node], e = offs[node + 1];
  int half = lane >> 5;          // lanes 0-31: even edges, 32-63: odd edges
  int l4 = (lane & 31) << 2;     // 4 cols per lane
  float a0 = 0.f, a1 = 0.f, a2 = 0.f, a3 = 0.f;
  int j = s + half;
  for (; j + 2 < e; j += 4) {
    int r0 = eidx[j], r1 = eidx[j + 2];
    bf16x4 v0 = *(const bf16x4*)(feat + (size_t)r0 * 128 + l4);
    bf16x4 v1 = *(const bf16x4*)(feat + (size_t)r1 * 128 + l4);
    a0 += (float)v0[0] + (float)v1[0];
    a1 += (float)v0[1] + (float)v1[1];
    a2 += (float)v0[2] + (float)v1[2];
    a3 += (float)v0[3] + (float)v1[3];
  }
  if (j < e) {
    int r0 = eidx[j];
    bf16x4 v0 = *(const bf16x4*)(feat + (size_t)r0 * 128 + l4);
    a0 += (float)v0[0]; a1 += (float)v0[1]; a2 += (float)v0[2]; a3 += (float)v0[3];
  }
  a0 += __shfl_xor(a0, 32, 64);
  a1 += __shfl_xor(a1, 32, 64);
  a2 += __shfl_xor(a2, 32, 64);
  a3 += __shfl_xor(a3, 32, 64);
  if (half == 0) {
    float inv = (e > s) ? (1.f / (float)(e - s)) : 0.f;
    bf16x4 o;
    o[0] = (__bf16)(a0 * inv); o[1] = (__bf16)(a1 * inv);
    o[2] = (__bf16)(a2 * inv); o[3] = (__bf16)(a3 * inv);
    *(bf16x4*)(out + (size_t)orow * 128 + l4) = o;
  }
}

// ---------------- persistent kernel B: build + L1 aggregation ----------------
// phases: P0 prep/transpose/cvt/hist | P1 scan1 | P2 scan2/3 | P3 fill | P4 seg1
__global__ __launch_bounds__(256, 4)
void coopB(const float* __restrict__ W1l, const float* __restrict__ W1r,
           const float* __restrict__ W2l, const float* __restrict__ W2r,
           const float* __restrict__ b1, const float* __restrict__ b2,
           const float* __restrict__ predW,
           const float* __restrict__ emb_user, const float* __restrict__ emb_item,
           const int* __restrict__ ug_src, const int* __restrict__ ug_dst,
           const int* __restrict__ ui_src, const int* __restrict__ ui_dst,
           const int* __restrict__ gi_src, const int* __restrict__ gi_dst,
           char* __restrict__ ws) {
  __shared__ float tbuf[64][65];
  __shared__ int shi[8];
  int tid = threadIdx.x;
  int nb = gridDim.x;
  int* bar = (int*)(ws + B_BAR);

  __bf16* WT = (__bf16*)(ws + B_WT);
  float* bc  = (float*)(ws + B_BC);
  __bf16* pwt = (__bf16*)(ws + B_PWT);
  __bf16* embU = (__bf16*)(ws + B_EMBU);
  __bf16* embI = (__bf16*)(ws + B_EMBI);
  int* cnt  = (int*)(ws + B_CNT);
  int* offs = (int*)(ws + B_OFFS);
  int* cur  = (int*)(ws + B_CUR);
  int* eidx = (int*)(ws + B_EIDX);
  int* chunksum = (int*)(ws + B_AGGU);   // scratch overlap, dead until seg1

  // P0: prep weights + transpose predW + cvt embeddings + edge histogram
  // (cnt zeroed by the host-side memset that also zeroes the barrier)
  for (int vb = blockIdx.x; vb < NB_P1; vb += nb) {
    int b = vb;
    if (b < NB_PREP) { prep_dev(W1l, W1r, W2l, W2r, b1, b2, WT, bc, b, tid); continue; }
    b -= NB_PREP;
    if (b < NB_TP) { transpose_dev(predW, pwt, b % 313, b / 313, tid, tbuf); continue; }
    b -= NB_TP;
    if (b < NB_CVU) { cvt_dev(emb_user, embU, b, tid, NU * 32); continue; }
    b -= NB_CVU;
    if (b < NB_CVI) { cvt_dev(emb_item, embI, b, tid, NI * 32); continue; }
    b -= NB_CVI;
    hist_dev(ug_dst, gi_src, ui_src, ui_dst, cnt, b, tid);
  }
  gbar(bar, nb);

  // P1: per-chunk sums
  for (int vb = blockIdx.x; vb < NCHUNK; vb += nb) {
    int lane = tid & 63, w = tid >> 6;
    int base = vb * SCAN_CHUNK + tid * 8;
    int s = 0;
#pragma unroll
    for (int j = 0; j < 8; ++j) { int i = base + j; if (i < NN) s += cnt[i]; }
#pragma unroll
    for (int d = 1; d < 64; d <<= 1) s += __shfl_xor(s, d, 64);
    if (lane == 0) shi[w] = s;
    __syncthreads();
    if (tid == 0) chunksum[vb] = shi[0] + shi[1] + shi[2] + shi[3];
    __syncthreads();
  }
  gbar(bar, nb);

  // P2: chunk-base prefix (recomputed per block) + local scan -> offs, cur
  for (int vb = blockIdx.x; vb < NCHUNK; vb += nb) {
    int lane = tid & 63, w = tid >> 6;
    if (w == 0) {
      int v = chunksum[lane];
      int incl = v;
#pragma unroll
      for (int d = 1; d < 64; d <<= 1) { int t = __shfl_up(incl, d, 64); if (lane >= d) incl += t; }
      if (lane == vb) shi[4] = incl - v;
    }
    int base = vb * SCAN_CHUNK + tid * 8;
    int x[8]; int s = 0;
#pragma unroll
    for (int j = 0; j < 8; ++j) { int i = base + j; x[j] = (i < NN) ? cnt[i] : 0; s += x[j]; }
    int incl = s;
#pragma unroll
    for (int d = 1; d < 64; d <<= 1) { int t = __shfl_up(incl, d, 64); if (lane >= d) incl += t; }
    if (lane == 63) shi[w] = incl;
    __syncthreads();
    int wpre = 0;
    for (int ww = 0; ww < w; ++ww) wpre += shi[ww];
    int excl = shi[4] + wpre + incl - s;
#pragma unroll
    for (int j = 0; j < 8; ++j) {
      int i = base + j;
      if (i < NN) { offs[i] = excl; cur[i] = excl; }
      excl += x[j];
      if (i == NN - 1) offs[NN] = excl;
    }
    __syncthreads();
  }
  gbar(bar, nb);

  // P3: fill edge index (atomic slot allocation)
  for (int i = blockIdx.x * 256 + tid; i < ETOT; i += nb * 256) {
    int key, base, payload;
    if (i < EUG)                  { key = ug_dst[i];       base = 0;            payload = ug_src[i]; }
    else if (i < EUG + EGI)       { int j = i - EUG;       key = gi_src[j]; base = NG;          payload = gi_dst[j]; }
    else if (i < EUG + EGI + EUI) { int j = i - EUG - EGI; key = ui_src[j]; base = 2 * NG;      payload = ui_dst[j]; }
    else                          { int j = i - EUG - EGI - EUI; key = ui_dst[j]; base = 2 * NG + NU; payload = ui_src[j]; }
    int pos = atomicAdd(&cur[base + key], 1);
    eidx[pos] = payload;
  }
  gbar(bar, nb);

  // P4: layer-1 segment means (all four edge types; raw features)
  {
    int w = tid >> 6, lane = tid & 63;
    __bf16* aggU = (__bf16*)(ws + B_AGGU);
    __bf16* aggI = (__bf16*)(ws + B_AGGI);
    __bf16* aggG1 = (__bf16*)(ws + B_AGGG1);
    __bf16* aggG2 = (__bf16*)(ws + B_AGGG2);
    for (int node = blockIdx.x * 4 + w; node < NN; node += nb * 4) {
      const __bf16* feat; __bf16* out; int orow;
      if (node < NG)               { feat = embU; out = aggG1; orow = node; }
      else if (node < 2 * NG)      { feat = embI; out = aggG2; orow = node - NG; }
      else if (node < 2 * NG + NU) { feat = embI; out = aggU;  orow = node - 2 * NG; }
      else                         { feat = embU; out = aggI;  orow = node - 2 * NG - NU; }
      seg_dev(feat, offs, eidx, out, node, orow, lane);
    }
  }
}

// ---------------- persistent kernel C: GEMMs + L2 aggregation + output --------
// phases: P5 gemm1 (hu1/hi1/hg1) | P6 seg2 | P7 gemm2 | P8 gemmF
__global__ __launch_bounds__(256, 2)
void coopC(char* __restrict__ ws, const float* __restrict__ predb,
           float* __restrict__ out) {
  __shared__ char smem[65536];
  int nb = gridDim.x;
  int* bar = (int*)(ws + B_BAR);

  const __bf16* WT = (const __bf16*)(ws + B_WT);
  const float* bc  = (const float*)(ws + B_BC);
  const int* offs = (const int*)(ws + B_OFFS);
  const int* eidx = (const int*)(ws + B_EIDX);
  __bf16* embU = (__bf16*)(ws + B_EMBU);
  __bf16* embI = (__bf16*)(ws + B_EMBI);
  __bf16* aggU = (__bf16*)(ws + B_AGGU);
  __bf16* aggI = (__bf16*)(ws + B_AGGI);
  __bf16* aggG1 = (__bf16*)(ws + B_AGGG1);
  __bf16* aggG2 = (__bf16*)(ws + B_AGGG2);
  __bf16* hg1 = (__bf16*)(ws + B_HG1);
  __bf16* gU  = (__bf16*)(ws + B_GU);
  __bf16* gI  = (__bf16*)(ws + B_GI);
  __bf16* rep = (__bf16*)(ws + B_REP);
  const __bf16* pwt = (const __bf16*)(ws + B_PWT);

  // P5: layer-1 GEMMs (hu1 in aggU, hi1 in aggI, hg1)
  for (int vb = blockIdx.x; vb < NBU + NBI + NBG; vb += nb) {
    if (vb < NBU) {
      gemm_core(embU, WT + 0 * 16384, aggU, WT + 1 * 16384, nullptr, nullptr,
                bc + 0, nullptr, aggU, NU, 128, 2, 1, vb, 0, smem);
    } else if (vb < NBU + NBI) {
      gemm_core(aggI, WT + 2 * 16384, embI, WT + 3 * 16384, nullptr, nullptr,
                bc + 128, nullptr, aggI, NI, 128, 2, 1, vb - NBU, 0, smem);
    } else {
      gemm_core(aggG1, WT + 4 * 16384, aggG2, WT + 5 * 16384, nullptr, nullptr,
                bc + 256, nullptr, hg1, NG, 128, 2, 1, vb - NBU - NBI, 0, smem);
    }
  }
  gbar(bar, nb);

  // P6: layer-2 group aggregations (u->g of hu1, i->g of hi1)
  {
    int w = threadIdx.x >> 6, lane = threadIdx.x & 63;
    for (int node = blockIdx.x * 4 + w; node < 2 * NG; node += nb * 4) {
      const __bf16* feat; __bf16* outp; int orow;
      if (node < NG) { feat = aggU; outp = gU; orow = node; }
      else           { feat = aggI; outp = gI; orow = node - NG; }
      seg_dev(feat, offs, eidx, outp, node, orow, lane);
    }
  }
  gbar(bar, nb);

  // P7: layer-2 group GEMM -> rep
  for (int vb = blockIdx.x; vb < NBG; vb += nb) {
    gemm_core(gU, WT + 7 * 16384, hg1, WT + 6 * 16384, gI, WT + 8 * 16384,
              bc + 384, nullptr, rep, NG, 128, 3, 1, vb, 0, smem);
  }
  gbar(bar, nb);

  // P8: final prediction GEMM -> out [NG, NI] fp32 (NT stores)
  for (int vb = blockIdx.x; vb < NBG * NBI; vb += nb) {
    int rb = vb / NBI, cb = vb % NBI;
    gemm_core(rep, pwt, nullptr, nullptr, nullptr, nullptr,
              predb, out, nullptr, NG, NI, 1, 0, rb, cb, smem);
  }
}

// ---------------- launch ----------------
extern "C" void kernel_launch(void* const* d_in, const int* in_sizes, int n_in,
                              void* d_out, int out_size, void* d_ws, size_t ws_size,
                              hipStream_t stream) {
  const float* emb_user = (const float*)d_in[4];
  const float* emb_item = (const float*)d_in[5];
  const float* W1l = (const float*)d_in[6];
  const float* W1r = (const float*)d_in[7];
  const float* b1  = (const float*)d_in[8];
  const float* W2l = (const float*)d_in[9];
  const float* W2r = (const float*)d_in[10];
  const float* b2  = (const float*)d_in[11];
  const float* predW = (const float*)d_in[12];
  const float* predb = (const float*)d_in[13];
  const int* ug_src = (const int*)d_in[14];
  const int* ug_dst = (const int*)d_in[15];
  const int* ui_src = (const int*)d_in[16];
  const int* ui_dst = (const int*)d_in[17];
  const int* gi_src = (const int*)d_in[18];
  const int* gi_dst = (const int*)d_in[19];

  char* ws = (char*)d_ws;

  // zero barrier (128 B) + cnt (NN ints) in one contiguous memset
  hipMemsetAsync(ws + B_BAR, 0, 128 + NN * sizeof(int), stream);

  coopB<<<GRID_B, 256, 0, stream>>>(W1l, W1r, W2l, W2r, b1, b2, predW,
                                    emb_user, emb_item,
                                    ug_src, ug_dst, ui_src, ui_dst,
                                    gi_src, gi_dst, ws);
  coopC<<<GRID_C, 256, 0, stream>>>(ws, predb, (float*)d_out);
}